// Round 1
// baseline (63.707 us; speedup 1.0000x reference)
//
#include <hip/hip_runtime.h>
#include <math.h>

#define G1C 3.0f
#define G2C 5.0f
#define THRC 0.05f
#define ITILE 256
#define JTILE 512

// Compute per-element quantities for element n of batch b.
__device__ __forceinline__ void elem_vals(
    const float* __restrict__ cls, const float* __restrict__ label_cls,
    const float* __restrict__ label_loc, const float* __restrict__ pred,
    float tx1, float ty1, float tx2, float ty2,
    int b, int n, int N, int flag,
    float& c, float& prob, float& iou, bool& pos)
{
    const float* ll = label_loc + (size_t)b * 4 * N;
    float l  = ll[0 * N + n];
    float t  = ll[1 * N + n];
    float r  = ll[2 * N + n];
    float bo = ll[3 * N + n];
    float mnlr = fminf(l, r),  mxlr = fmaxf(l, r);
    float mntb = fminf(t, bo), mxtb = fmaxf(t, bo);
    c = sqrtf((mnlr / mxlr) * (mntb / mxtb));

    pos = label_cls[(size_t)b * N + n] > 0.0f;

    float p = cls[((size_t)b * N + n) * 2 + 1];
    prob = flag ? p : expf(p);

    const float* pb = pred + (size_t)b * 4 * N;
    float x1 = pb[0 * N + n], y1 = pb[1 * N + n];
    float x2 = pb[2 * N + n], y2 = pb[3 * N + n];
    float ww = fmaxf(fminf(tx2, x2) - fmaxf(tx1, x1), 0.0f);
    float hh = fmaxf(fminf(ty2, y2) - fmaxf(ty1, y1), 0.0f);
    float area  = (x2 - x1) * (y2 - y1);
    float tarea = (tx2 - tx1) * (ty2 - ty1);
    float inter = ww * hh;
    iou = inter / (area + tarea - inter);
}

__global__ __launch_bounds__(ITILE) void pairwise_kernel(
    const float* __restrict__ cls, const float* __restrict__ label_cls,
    const float* __restrict__ label_loc, const float* __restrict__ pred,
    const float* __restrict__ tgt, const int* __restrict__ flagp,
    int N,
    double* __restrict__ part1, double* __restrict__ part2,
    unsigned int* __restrict__ partc)
{
    __shared__ float sC[JTILE];
    __shared__ float sB[JTILE];
    __shared__ float sD[JTILE];
    __shared__ double r1[ITILE];
    __shared__ double r2[ITILE];
    __shared__ int   rk[ITILE];

    const int b   = blockIdx.z;
    const int tid = threadIdx.x;
    const int flag = *flagp;

    const float tx1 = tgt[b * 4 + 0], ty1 = tgt[b * 4 + 1];
    const float tx2 = tgt[b * 4 + 2], ty2 = tgt[b * 4 + 3];

    // ---- stage j-tile into LDS: c_j (INF if !pos), B_j = exp(G1*p_j), D_j = exp(G2*iou_j)
    const int jbase = blockIdx.y * JTILE;
    for (int t = tid; t < JTILE; t += ITILE) {
        int j = jbase + t;
        if (j < N) {
            float c, prob, iou; bool pos;
            elem_vals(cls, label_cls, label_loc, pred, tx1, ty1, tx2, ty2,
                      b, j, N, flag, c, prob, iou, pos);
            sC[t] = pos ? c : INFINITY;
            sB[t] = expf(G1C * prob);
            sD[t] = expf(G2C * iou);
        } else {
            sC[t] = INFINITY;
            sB[t] = 0.0f;
            sD[t] = 0.0f;
        }
    }

    // ---- own i-side values
    const int i  = blockIdx.x * ITILE + tid;
    const int ic = (i < N) ? i : (N - 1);  // clamp for safe loads
    float ci, probi, ioui; bool posi;
    elem_vals(cls, label_cls, label_loc, pred, tx1, ty1, tx2, ty2,
              b, ic, N, flag, ci, probi, ioui, posi);
    const float Ai = expf(-G1C * probi);
    const float Ci = expf(-G2C * ioui);
    // threshold encodes the pos_i & in-bounds mask: -INF makes all compares false
    const float cthr = (posi && i < N) ? (ci - THRC) : -INFINITY;

    __syncthreads();

    // ---- inner loop over j-tile: compare + predicated accumulate (no exp here)
    float accB = 0.0f, accD = 0.0f;
    int k = 0;
#pragma unroll 8
    for (int t = 0; t < JTILE; ++t) {
        float cj = sC[t];
        bool m = cj < cthr;
        accB += m ? sB[t] : 0.0f;
        accD += m ? sD[t] : 0.0f;
        k += m ? 1 : 0;
    }

    // ---- block reduction (deterministic, no atomics)
    r1[tid] = (double)Ai * (double)accB;
    r2[tid] = (double)Ci * (double)accD;
    rk[tid] = k;
    __syncthreads();
    for (int s = ITILE / 2; s > 0; s >>= 1) {
        if (tid < s) {
            r1[tid] += r1[tid + s];
            r2[tid] += r2[tid + s];
            rk[tid] += rk[tid + s];
        }
        __syncthreads();
    }
    if (tid == 0) {
        int pidx = (b * gridDim.y + blockIdx.y) * gridDim.x + blockIdx.x;
        part1[pidx] = r1[0];
        part2[pidx] = r2[0];
        partc[pidx] = (unsigned int)rk[0];
    }
}

__global__ void finalize_kernel(
    const double* __restrict__ part1, const double* __restrict__ part2,
    const unsigned int* __restrict__ partc,
    int B, int nper, float* __restrict__ out)
{
    if (threadIdx.x == 0 && blockIdx.x == 0) {
        double f1 = 0.0, f2 = 0.0;
        int nvalid = 0;
        for (int b = 0; b < B; ++b) {
            double s1 = 0.0, s2 = 0.0;
            unsigned long long c = 0;
            for (int t = 0; t < nper; ++t) {
                int idx = b * nper + t;
                s1 += part1[idx];
                s2 += part2[idx];
                c  += partc[idx];
            }
            if (c > 0) {
                f1 += s1 / (double)c;
                f2 += s2 / (double)c;
                ++nvalid;
            }
        }
        if (nvalid > 0) {
            out[0] = (float)(f1 / (double)nvalid);
            out[1] = (float)(f2 / (double)nvalid);
        } else {
            out[0] = 0.0f;
            out[1] = 0.0f;
        }
    }
}

extern "C" void kernel_launch(void* const* d_in, const int* in_sizes, int n_in,
                              void* d_out, int out_size, void* d_ws, size_t ws_size,
                              hipStream_t stream) {
    const float* cls       = (const float*)d_in[0];
    const float* label_cls = (const float*)d_in[1];
    const float* label_loc = (const float*)d_in[2];
    const float* pred      = (const float*)d_in[3];
    const float* tgt       = (const float*)d_in[4];
    const int*   flagp     = (const int*)d_in[5];

    const int B = in_sizes[4] / 4;          // label_target is (B,4)
    const int N = in_sizes[1] / B;          // label_cls is (B,N)

    const int gx = (N + ITILE - 1) / ITILE;
    const int gy = (N + JTILE - 1) / JTILE;
    const int nper = gx * gy;
    const size_t npart = (size_t)B * nper;

    double* part1 = (double*)d_ws;
    double* part2 = part1 + npart;
    unsigned int* partc = (unsigned int*)(part2 + npart);

    float* out = (float*)d_out;

    dim3 grid(gx, gy, B);
    dim3 block(ITILE);
    pairwise_kernel<<<grid, block, 0, stream>>>(
        cls, label_cls, label_loc, pred, tgt, flagp, N, part1, part2, partc);
    finalize_kernel<<<1, 64, 0, stream>>>(part1, part2, partc, B, nper, out);
}

// Round 2
// 17.439 us; speedup vs baseline: 3.6531x; 3.6531x over previous
//
#include <hip/hip_runtime.h>
#include <math.h>

#define G1C 3.0f
#define G2C 5.0f
#define THRC 0.05f
#define BLK 256      // threads per block
#define IPT 4        // i's per thread -> 1024 i per block
#define JT  64       // j-tile staged in LDS

// Compute per-element quantities for element n of batch b.
__device__ __forceinline__ void elem_vals(
    const float* __restrict__ cls, const float* __restrict__ label_cls,
    const float* __restrict__ label_loc, const float* __restrict__ pred,
    float tx1, float ty1, float tx2, float ty2,
    int b, int n, int N, int flag,
    float& c, float& prob, float& iou, bool& pos)
{
    const float* ll = label_loc + (size_t)b * 4 * N;
    float l  = ll[0 * N + n];
    float t  = ll[1 * N + n];
    float r  = ll[2 * N + n];
    float bo = ll[3 * N + n];
    float mnlr = fminf(l, r),  mxlr = fmaxf(l, r);
    float mntb = fminf(t, bo), mxtb = fmaxf(t, bo);
    c = sqrtf((mnlr / mxlr) * (mntb / mxtb));

    pos = label_cls[(size_t)b * N + n] > 0.0f;

    float p = cls[((size_t)b * N + n) * 2 + 1];
    prob = flag ? p : expf(p);

    const float* pb = pred + (size_t)b * 4 * N;
    float x1 = pb[0 * N + n], y1 = pb[1 * N + n];
    float x2 = pb[2 * N + n], y2 = pb[3 * N + n];
    float ww = fmaxf(fminf(tx2, x2) - fmaxf(tx1, x1), 0.0f);
    float hh = fmaxf(fminf(ty2, y2) - fmaxf(ty1, y1), 0.0f);
    float area  = (x2 - x1) * (y2 - y1);
    float tarea = (tx2 - tx1) * (ty2 - ty1);
    float inter = ww * hh;
    iou = inter / (area + tarea - inter);
}

__global__ __launch_bounds__(BLK) void pairwise_kernel(
    const float* __restrict__ cls, const float* __restrict__ label_cls,
    const float* __restrict__ label_loc, const float* __restrict__ pred,
    const float* __restrict__ tgt, const int* __restrict__ flagp,
    int N,
    double* __restrict__ part1, double* __restrict__ part2,
    unsigned int* __restrict__ partc)
{
    __shared__ float4 sJ[JT];           // {c_j (INF if !pos), exp(G1 p_j), exp(G2 iou_j), 0}
    __shared__ double w1[BLK / 64];
    __shared__ double w2[BLK / 64];
    __shared__ unsigned int wk[BLK / 64];

    const int b    = blockIdx.z;
    const int tid  = threadIdx.x;
    const int flag = *flagp;

    const float tx1 = tgt[b * 4 + 0], ty1 = tgt[b * 4 + 1];
    const float tx2 = tgt[b * 4 + 2], ty2 = tgt[b * 4 + 3];

    // ---- stage j-tile (one thread per j)
    const int jbase = blockIdx.y * JT;
    if (tid < JT) {
        int j = jbase + tid;
        if (j < N) {
            float c, prob, iou; bool pos;
            elem_vals(cls, label_cls, label_loc, pred, tx1, ty1, tx2, ty2,
                      b, j, N, flag, c, prob, iou, pos);
            sJ[tid] = make_float4(pos ? c : INFINITY, expf(G1C * prob), expf(G2C * iou), 0.0f);
        } else {
            sJ[tid] = make_float4(INFINITY, 0.0f, 0.0f, 0.0f);
        }
    }

    // ---- own i-side values (IPT per thread, stride BLK for coalescing)
    float cthr[IPT], Ai[IPT], Ci[IPT];
    const int ibase = blockIdx.x * (BLK * IPT) + tid;
#pragma unroll
    for (int q = 0; q < IPT; ++q) {
        int i  = ibase + q * BLK;
        int ic = (i < N) ? i : (N - 1);
        float c, prob, iou; bool pos;
        elem_vals(cls, label_cls, label_loc, pred, tx1, ty1, tx2, ty2,
                  b, ic, N, flag, c, prob, iou, pos);
        Ai[q]   = expf(-G1C * prob);
        Ci[q]   = expf(-G2C * iou);
        cthr[q] = (pos && i < N) ? (c - THRC) : -INFINITY;
    }

    __syncthreads();

    // ---- inner loop: 1 broadcast ds_read_b128 feeds 4 pairs
    float aB[IPT], aD[IPT];
    int   kc[IPT];
#pragma unroll
    for (int q = 0; q < IPT; ++q) { aB[q] = 0.0f; aD[q] = 0.0f; kc[q] = 0; }

#pragma unroll 8
    for (int t = 0; t < JT; ++t) {
        float4 v = sJ[t];
#pragma unroll
        for (int q = 0; q < IPT; ++q) {
            bool m = v.x < cthr[q];
            aB[q] += m ? v.y : 0.0f;
            aD[q] += m ? v.z : 0.0f;
            kc[q] += m ? 1 : 0;
        }
    }

    // ---- per-thread combine, then wave shuffle reduce (deterministic)
    double s1 = 0.0, s2 = 0.0;
    int kk = 0;
#pragma unroll
    for (int q = 0; q < IPT; ++q) {
        s1 += (double)Ai[q] * (double)aB[q];
        s2 += (double)Ci[q] * (double)aD[q];
        kk += kc[q];
    }
#pragma unroll
    for (int off = 32; off >= 1; off >>= 1) {
        s1 += __shfl_down(s1, off, 64);
        s2 += __shfl_down(s2, off, 64);
        kk += __shfl_down(kk, off, 64);
    }
    const int wid = tid >> 6, lane = tid & 63;
    if (lane == 0) { w1[wid] = s1; w2[wid] = s2; wk[wid] = (unsigned int)kk; }
    __syncthreads();
    if (tid == 0) {
        double t1 = 0.0, t2 = 0.0; unsigned int tk = 0;
#pragma unroll
        for (int w = 0; w < BLK / 64; ++w) { t1 += w1[w]; t2 += w2[w]; tk += wk[w]; }
        int pidx = (b * gridDim.y + blockIdx.y) * gridDim.x + blockIdx.x;
        part1[pidx] = t1;
        part2[pidx] = t2;
        partc[pidx] = tk;
    }
}

// one wave (64 lanes) per batch
__global__ void finalize_kernel(
    const double* __restrict__ part1, const double* __restrict__ part2,
    const unsigned int* __restrict__ partc,
    int B, int nper, float* __restrict__ out)
{
    __shared__ double l1s[32], l2s[32];
    __shared__ int    vld[32];
    const int b = threadIdx.x >> 6, lane = threadIdx.x & 63;
    double s1 = 0.0, s2 = 0.0;
    unsigned long long c = 0;
    if (b < B) {
        for (int t = lane; t < nper; t += 64) {
            int idx = b * nper + t;
            s1 += part1[idx];
            s2 += part2[idx];
            c  += partc[idx];
        }
    }
#pragma unroll
    for (int off = 32; off >= 1; off >>= 1) {
        s1 += __shfl_down(s1, off, 64);
        s2 += __shfl_down(s2, off, 64);
        c  += __shfl_down(c,  off, 64);
    }
    if (b < B && lane == 0) {
        l1s[b] = (c > 0) ? s1 / (double)c : 0.0;
        l2s[b] = (c > 0) ? s2 / (double)c : 0.0;
        vld[b] = (c > 0) ? 1 : 0;
    }
    __syncthreads();
    if (threadIdx.x == 0) {
        double f1 = 0.0, f2 = 0.0; int nv = 0;
        for (int bb = 0; bb < B; ++bb) { f1 += l1s[bb]; f2 += l2s[bb]; nv += vld[bb]; }
        if (nv > 0) {
            out[0] = (float)(f1 / (double)nv);
            out[1] = (float)(f2 / (double)nv);
        } else {
            out[0] = 0.0f;
            out[1] = 0.0f;
        }
    }
}

extern "C" void kernel_launch(void* const* d_in, const int* in_sizes, int n_in,
                              void* d_out, int out_size, void* d_ws, size_t ws_size,
                              hipStream_t stream) {
    const float* cls       = (const float*)d_in[0];
    const float* label_cls = (const float*)d_in[1];
    const float* label_loc = (const float*)d_in[2];
    const float* pred      = (const float*)d_in[3];
    const float* tgt       = (const float*)d_in[4];
    const int*   flagp     = (const int*)d_in[5];

    const int B = in_sizes[4] / 4;          // label_target is (B,4)
    const int N = in_sizes[1] / B;          // label_cls is (B,N)

    const int gx = (N + BLK * IPT - 1) / (BLK * IPT);
    const int gy = (N + JT - 1) / JT;
    const int nper = gx * gy;
    const size_t npart = (size_t)B * nper;

    double* part1 = (double*)d_ws;
    double* part2 = part1 + npart;
    unsigned int* partc = (unsigned int*)(part2 + npart);

    float* out = (float*)d_out;

    dim3 grid(gx, gy, B);
    dim3 block(BLK);
    pairwise_kernel<<<grid, block, 0, stream>>>(
        cls, label_cls, label_loc, pred, tgt, flagp, N, part1, part2, partc);
    finalize_kernel<<<1, 64 * B, 0, stream>>>(part1, part2, partc, B, nper, out);
}